// Round 2
// baseline (482.882 us; speedup 1.0000x reference)
//
#include <hip/hip_runtime.h>
#include <hip/hip_bf16.h>

// Problem constants
#define PB 4
#define PN 2048
#define PD 1024
#define PH 16
#define PHD 64
#define NSC 11

typedef __attribute__((ext_vector_type(8))) short short8;
typedef __attribute__((ext_vector_type(4))) float floatx4;

#define AS1 __attribute__((address_space(1)))
#define AS3 __attribute__((address_space(3)))

static __device__ __forceinline__ unsigned short bf16bits(float f) {
    __hip_bfloat16 h = __float2bfloat16(f);
    return __builtin_bit_cast(unsigned short, h);
}

// ---------------- cast kernels ----------------
__global__ void cast_f32_to_bf16_v4(const float4* __restrict__ in,
                                    ushort4* __restrict__ out, int n4) {
    int i = blockIdx.x * blockDim.x + threadIdx.x;
    if (i < n4) {
        float4 v = in[i];
        ushort4 o;
        o.x = bf16bits(v.x);
        o.y = bf16bits(v.y);
        o.z = bf16bits(v.z);
        o.w = bf16bits(v.w);
        out[i] = o;
    }
}

// casts W_qkv (3M) + W_gate (1M) into wcomb, W_out (1M) into wout
__global__ void cast_weights(const float4* __restrict__ wqkv,
                             const float4* __restrict__ wgate,
                             const float4* __restrict__ wout,
                             ushort4* __restrict__ wcomb,
                             ushort4* __restrict__ woutb) {
    int i = blockIdx.x * blockDim.x + threadIdx.x;  // 0 .. 5M/4
    const int QKV4 = 3 * PD * PD / 4;
    const int G4 = PD * PD / 4;
    float4 v;
    ushort4* dst;
    if (i < QKV4) {
        v = wqkv[i];
        dst = wcomb + i;
    } else if (i < QKV4 + G4) {
        v = wgate[i - QKV4];
        dst = wcomb + i;
    } else {
        v = wout[i - QKV4 - G4];
        dst = woutb + (i - QKV4 - G4);
    }
    ushort4 o;
    o.x = bf16bits(v.x);
    o.y = bf16bits(v.y);
    o.z = bf16bits(v.z);
    o.w = bf16bits(v.w);
    *dst = o;
}

// gated = bf16(att * sigmoid(gatep)) — pure HBM stream
__global__ void gate_mul(const float4* __restrict__ att,
                         const float4* __restrict__ gatep,
                         ushort4* __restrict__ gated, int n4) {
    int i = blockIdx.x * blockDim.x + threadIdx.x;
    if (i < n4) {
        float4 a = att[i];
        float4 gp = gatep[i];
        ushort4 o;
        o.x = bf16bits(a.x / (1.f + __expf(-gp.x)));
        o.y = bf16bits(a.y / (1.f + __expf(-gp.y)));
        o.z = bf16bits(a.z / (1.f + __expf(-gp.z)));
        o.w = bf16bits(a.w / (1.f + __expf(-gp.w)));
        gated[i] = o;
    }
}

// ---------------- GEMM 128x128: C = A @ B^T + bias, dual output ----------------
// A: [M,K] bf16 row-major; Bm: [Nn,K] bf16 row-major (W[out][in]).
// Columns < split  -> out1 (row stride N1), bias b1
// Columns >= split -> out2 (row stride N2), bias b2   (split is 128-aligned,
// so the branch is block-uniform)
#define GBM 128
#define GBN 128
#define GBK 64

__global__ __launch_bounds__(256) void gemm_bt128(
    const __hip_bfloat16* __restrict__ A,
    const __hip_bfloat16* __restrict__ Bm,
    const float* __restrict__ b1,
    const float* __restrict__ b2,
    int split,
    float* __restrict__ out1, int N1,
    float* __restrict__ out2, int N2,
    int K) {
    __shared__ alignas(16) __hip_bfloat16 sA[GBM * GBK];
    __shared__ alignas(16) __hip_bfloat16 sB[GBN * GBK];

    const int tid = threadIdx.x;
    const int lane = tid & 63;
    const int wave = tid >> 6;   // 0..3
    const int wy = wave >> 1;    // 0..1
    const int wx = wave & 1;     // 0..1

    // staging: each global_load_lds covers 8 rows x 64 elems (1 KiB)
    const int lrow8 = lane >> 3;                 // 0..7
    const int lchunk = lane & 7;                 // LDS chunk slot (8 elems)
    const int gchunk = lchunk ^ lrow8;           // global chunk fetched into slot

    const int r16 = lane & 15;
    const int qd = lane >> 4;
    const int sw = r16 & 7;  // reader swizzle key

    floatx4 acc[4][4];
#pragma unroll
    for (int i = 0; i < 4; i++)
#pragma unroll
        for (int j = 0; j < 4; j++) acc[i][j] = (floatx4){0.f, 0.f, 0.f, 0.f};

    const size_t arow0 = (size_t)blockIdx.y * GBM;
    const size_t brow0 = (size_t)blockIdx.x * GBN;

    for (int k0 = 0; k0 < K; k0 += GBK) {
        __syncthreads();  // previous ds_reads done before overwrite
#pragma unroll
        for (int half = 0; half < 4; half++) {
            const int rbase = wave * 8 + half * 32;  // wave-uniform
            const __hip_bfloat16* gA =
                A + (arow0 + rbase + lrow8) * K + k0 + gchunk * 8;
            __builtin_amdgcn_global_load_lds(
                (const AS1 unsigned int*)(const void*)gA,
                (AS3 unsigned int*)(void*)(sA + rbase * GBK), 16, 0, 0);
            const __hip_bfloat16* gB =
                Bm + (brow0 + rbase + lrow8) * K + k0 + gchunk * 8;
            __builtin_amdgcn_global_load_lds(
                (const AS1 unsigned int*)(const void*)gB,
                (AS3 unsigned int*)(void*)(sB + rbase * GBK), 16, 0, 0);
        }
        __syncthreads();  // drain staging

#pragma unroll
        for (int kk = 0; kk < 2; kk++) {
            short8 af[4], bf[4];
            const int cs = (qd + 4 * kk);
#pragma unroll
            for (int i = 0; i < 4; i++)
                af[i] = *(const short8*)(sA + (wy * 64 + i * 16 + r16) * GBK +
                                         ((cs ^ sw) * 8));
#pragma unroll
            for (int j = 0; j < 4; j++)
                bf[j] = *(const short8*)(sB + (wx * 64 + j * 16 + r16) * GBK +
                                         ((cs ^ sw) * 8));
#pragma unroll
            for (int i = 0; i < 4; i++)
#pragma unroll
                for (int j = 0; j < 4; j++)
                    acc[i][j] = __builtin_amdgcn_mfma_f32_16x16x32_bf16(
                        af[i], bf[j], acc[i][j], 0, 0, 0);
        }
    }

#pragma unroll
    for (int i = 0; i < 4; i++) {
#pragma unroll
        for (int j = 0; j < 4; j++) {
            const int colb = (int)brow0 + wx * 64 + j * 16 + r16;
            const bool first = colb < split;
            const float bb = first ? b1[colb] : b2[colb - split];
            float* dst = first ? out1 : out2;
            const int nn = first ? N1 : N2;
            const int cc = first ? colb : colb - split;
#pragma unroll
            for (int e = 0; e < 4; e++) {
                const size_t row = arow0 + wy * 64 + i * 16 + qd * 4 + e;
                dst[row * (size_t)nn + cc] = acc[i][j][e] + bb;
            }
        }
    }
}

// ---------------- attention kernel (8 lanes / position, float8 per lane) ----
// Layout: 1 wave = 8 consecutive n positions; 8 lanes x float8 per position.
// qkv: [B, N, 3D] fp32 (q | k | v chunks of D); att: [B, N, D] fp32.
// R1 lesson: float8 restructure cut instrs but VGPR 68->128 dropped occupancy
// to 4 waves/SIMD -> latency-bound (VALUBusy 44%). This round: cap at 5
// waves/EU (VGPR<=102) and cut the redundant v-FMAs (all taps at one offset
// share the same v vector -> sum scalar weights first, one 8-FMA pass).

static constexpr int OFFS[21] = {1, 2, 3, 4, 6, 8, 12, 16, 24, 32, 48,
                                 64, 96, 128, 192, 256, 384, 512, 768, 1024, 1536};
static constexpr int U1J[21] = {0, 0, 0, 1, 1, 2, 2, 3, 3, 4, 4,
                                5, 5, 6, 6, 7, 7, 8, 8, 9, 9};
static constexpr int U1T[21] = {1, 2, 3, 2, 3, 2, 3, 2, 3, 2, 3,
                                2, 3, 2, 3, 2, 3, 2, 3, 2, 3};
// second user j (tau is always 1); -1 = none
static constexpr int U2J[21] = {-1, 1, -1, 2, -1, 3, -1, 4, -1, 5, -1,
                                6, -1, 7, -1, 8, -1, 9, -1, 10, -1};

static __device__ __forceinline__ float red8(float s) {
    // sum across each 8-lane group; all 8 lanes get the sum.
    // Pure-DPP chain (no LDS pipe, no lgkmcnt): xor1, xor2 butterflies then
    // row_half_mirror (lane i <-> 7-i within each 8-half) completes the sum.
    int t;
    // quad_perm [1,0,3,2] : lane ^ 1
    t = __builtin_amdgcn_update_dpp(0, __builtin_bit_cast(int, s), 0xB1, 0xF, 0xF, true);
    s += __builtin_bit_cast(float, t);
    // quad_perm [2,3,0,1] : lane ^ 2
    t = __builtin_amdgcn_update_dpp(0, __builtin_bit_cast(int, s), 0x4E, 0xF, 0xF, true);
    s += __builtin_bit_cast(float, t);
    // row_half_mirror : lane i <-> 7-i (within 8-lane half-row)
    t = __builtin_amdgcn_update_dpp(0, __builtin_bit_cast(int, s), 0x141, 0xF, 0xF, true);
    s += __builtin_bit_cast(float, t);
    return s;
}

__global__ __launch_bounds__(256, 5) void attn_kernel(
    const float* __restrict__ qkv,
    const float* __restrict__ scale_gain,       // [11,16]
    const float* __restrict__ W_qscale,         // [11,64]
    const float* __restrict__ identity_bypass,  // [16]
    const float* __restrict__ pos_bias,         // [44,16]
    float* __restrict__ att) {
    const int lane = threadIdx.x & 63;
    const int p = lane >> 3;   // position within wave, 0..7
    const int l = lane & 7;    // d-chunk (8 floats), 0..7

    const int flat = (blockIdx.x * 4 + (threadIdx.x >> 6)) * 8;  // first n of wave
    const int n = (flat & (PN - 1)) + p;
    const int h = (flat >> 11) & (PH - 1);
    const int b = flat >> 15;

    const size_t base_bn = (size_t)b * PN;
    const int col = h * PHD + l * 8;

    const float* qp = qkv + (base_bn + n) * (3 * PD) + col;
    const float4 qa = *(const float4*)qp;
    const float4 qb = *(const float4*)(qp + 4);
    const float4 k0a = *(const float4*)(qp + PD);
    const float4 k0b = *(const float4*)(qp + PD + 4);
    const float4 v0a = *(const float4*)(qp + 2 * PD);
    const float4 v0b = *(const float4*)(qp + 2 * PD + 4);

    auto dot8 = [](float4 a0, float4 a1, float4 b0, float4 b1) {
        float s = a0.x * b0.x;
        s = fmaf(a0.y, b0.y, s);
        s = fmaf(a0.z, b0.z, s);
        s = fmaf(a0.w, b0.w, s);
        s = fmaf(a1.x, b1.x, s);
        s = fmaf(a1.y, b1.y, s);
        s = fmaf(a1.z, b1.z, s);
        s = fmaf(a1.w, b1.w, s);
        return red8(s);
    };

    const float dot0 = dot8(qa, qb, k0a, k0b);  // k0 regs die here

    // gains = softmax(q @ W_qscale^T + scale_gain[:,h]) over 11 scales
    float g[NSC];
    float mx = -1e30f;
#pragma unroll
    for (int s = 0; s < NSC; s++) {
        const float* wp = W_qscale + s * PHD + l * 8;
        const float4 w0 = *(const float4*)wp;
        const float4 w1 = *(const float4*)(wp + 4);
        g[s] = dot8(qa, qb, w0, w1) + scale_gain[s * PH + h];
        mx = fmaxf(mx, g[s]);
    }
    float ssum = 0.f;
#pragma unroll
    for (int s = 0; s < NSC; s++) {
        g[s] = __expf(g[s] - mx);
        ssum += g[s];
    }
    const float inv = 1.f / ssum;
#pragma unroll
    for (int s = 0; s < NSC; s++) g[s] *= inv;

    const float D4c[4] = {0.4829629131445341f, 0.8365163037378079f,
                          0.2241438680420134f, -0.1294095225512604f};

    float4 o0, o1;
    float z;

    // ---- offset-0 block: 11 tau=0 taps + identity bypass, all scale v0.
    // Sum the 12 scalar weights first, then ONE 8-wide FMA pass.
    // All terms positive (coef0>0, feat>=0, g>=0, bp>=0) so z gets the same sum.
    {
        const float bp = log1pf(__expf(identity_bypass[h]));  // softplus
        const float f0 = (dot0 > 0.f ? dot0 : __expf(dot0) - 1.f) + 1.f;
        float wsum = bp * f0;
#pragma unroll
        for (int j = 0; j < NSC; j++) {
            const float xx = dot0 + pos_bias[(j * 4) * PH + h];
            const float feat = (xx > 0.f ? xx : __expf(xx) - 1.f) + 1.f;
            wsum = fmaf(g[j], D4c[0] * feat, wsum);
        }
        z = wsum;
        o0.x = wsum * v0a.x;
        o0.y = wsum * v0a.y;
        o0.z = wsum * v0a.z;
        o0.w = wsum * v0a.w;
        o1.x = wsum * v0b.x;
        o1.y = wsum * v0b.y;
        o1.z = wsum * v0b.z;
        o1.w = wsum * v0b.w;
    }  // v0 regs die here

    // ---- distinct nonzero offsets (each used by 1-2 taps, sharing k/v rows)
    // Masking: dv *= vm (padded rows dot to 0, matching reference zero-pad);
    // the combined out-weight is masked, v is NOT; z is UNmasked (reference
    // accumulates qk_feat for padded rows too).
#pragma unroll
    for (int t = 0; t < 21; t++) {
        const int off = OFFS[t];
        const bool valid = (n >= off);
        const int idx = valid ? (n - off) : 0;
        const float vm = valid ? 1.f : 0.f;
        const size_t rb = (base_bn + idx) * (3 * PD);
        const float* kp = qkv + rb + PD + col;
        const float* vp = qkv + rb + 2 * PD + col;
        const float4 k4a = *(const float4*)kp;
        const float4 k4b = *(const float4*)(kp + 4);
        const float4 v4a = *(const float4*)vp;
        const float4 v4b = *(const float4*)(vp + 4);
        const float dv = dot8(qa, qb, k4a, k4b) * vm;

        // user 1: (U1J[t], U1T[t])
        float wv, zacc;
        {
            const int j = U1J[t], tau = U1T[t];
            const float xx = dv + pos_bias[(j * 4 + tau) * PH + h];
            const float feat = (xx > 0.f ? xx : __expf(xx) - 1.f) + 1.f;
            const float wp = g[j] * (D4c[tau] * feat);
            zacc = fabsf(wp);  // = g * |coef| * feat  (g,feat >= 0)
            wv = wp;
        }
        // user 2: (U2J[t], tau=1) if present
        if (U2J[t] >= 0) {
            const int j = U2J[t];
            const float xx = dv + pos_bias[(j * 4 + 1) * PH + h];
            const float feat = (xx > 0.f ? xx : __expf(xx) - 1.f) + 1.f;
            const float wp = g[j] * (D4c[1] * feat);
            zacc += wp;  // coef > 0
            wv += wp;
        }
        z += zacc;
        wv *= vm;
        o0.x = fmaf(wv, v4a.x, o0.x);
        o0.y = fmaf(wv, v4a.y, o0.y);
        o0.z = fmaf(wv, v4a.z, o0.z);
        o0.w = fmaf(wv, v4a.w, o0.w);
        o1.x = fmaf(wv, v4b.x, o1.x);
        o1.y = fmaf(wv, v4b.y, o1.y);
        o1.z = fmaf(wv, v4b.z, o1.z);
        o1.w = fmaf(wv, v4b.w, o1.w);
    }

    const float zi = 1.f / (z + 1e-6f);
    float4 r0, r1;
    r0.x = o0.x * zi; r0.y = o0.y * zi; r0.z = o0.z * zi; r0.w = o0.w * zi;
    r1.x = o1.x * zi; r1.y = o1.y * zi; r1.z = o1.z * zi; r1.w = o1.w * zi;
    float* op = att + (base_bn + n) * PD + col;
    *(float4*)op = r0;
    *(float4*)(op + 4) = r1;
}

// ---------------- launch ----------------
extern "C" void kernel_launch(void* const* d_in, const int* in_sizes, int n_in,
                              void* d_out, int out_size, void* d_ws, size_t ws_size,
                              hipStream_t stream) {
    const float* x = (const float*)d_in[0];
    const float* W_qkv = (const float*)d_in[1];
    const float* b_qkv = (const float*)d_in[2];
    const float* W_out = (const float*)d_in[3];
    const float* b_out = (const float*)d_in[4];
    const float* W_gate = (const float*)d_in[5];
    const float* b_gate = (const float*)d_in[6];
    const float* scale_gain = (const float*)d_in[7];
    const float* W_qscale = (const float*)d_in[8];
    const float* identity_bypass = (const float*)d_in[9];
    const float* pos_bias = (const float*)d_in[10];
    float* out = (float*)d_out;

    const int M = PB * PN;  // 8192
    char* ws = (char*)d_ws;
    size_t off = 0;
    auto alloc = [&](size_t bytes) -> void* {
        void* p = ws + off;
        off += (bytes + 255) & ~(size_t)255;
        return p;
    };
    __hip_bfloat16* x_bf = (__hip_bfloat16*)alloc((size_t)M * PD * 2);
    __hip_bfloat16* wcomb_bf = (__hip_bfloat16*)alloc((size_t)4 * PD * PD * 2);
    __hip_bfloat16* wout_bf = (__hip_bfloat16*)alloc((size_t)PD * PD * 2);
    float* qkv = (float*)alloc((size_t)M * 3 * PD * 4);
    float* gate = (float*)alloc((size_t)M * PD * 4);
    float* att = (float*)alloc((size_t)M * PD * 4);
    __hip_bfloat16* gated = (__hip_bfloat16*)alloc((size_t)M * PD * 2);

    // casts
    cast_f32_to_bf16_v4<<<(M * PD / 4) / 256, 256, 0, stream>>>(
        (const float4*)x, (ushort4*)x_bf, M * PD / 4);
    cast_weights<<<(5 * PD * PD / 4) / 256, 256, 0, stream>>>(
        (const float4*)W_qkv, (const float4*)W_gate, (const float4*)W_out,
        (ushort4*)wcomb_bf, (ushort4*)wout_bf);

    // {qkv, gate} = x @ [W_qkv; W_gate]^T + {b_qkv, b_gate}
    gemm_bt128<<<dim3(4 * PD / GBN, M / GBM), 256, 0, stream>>>(
        x_bf, wcomb_bf, b_qkv, b_gate, 3 * PD, qkv, 3 * PD, gate, PD, PD);

    // attention -> att fp32 [8192, 1024]   (8 positions per wave, 32 per block)
    attn_kernel<<<(PB * PH * PN) / 32, 256, 0, stream>>>(
        qkv, scale_gain, W_qscale, identity_bypass, pos_bias, att);

    // gated = bf16(att * sigmoid(gate))  (elementwise, HBM-bound ~12 us)
    gate_mul<<<(M * PD / 4) / 256, 256, 0, stream>>>(
        (const float4*)att, (const float4*)gate, (ushort4*)gated, M * PD / 4);

    // out = gated @ W_out^T + b_out  -> fp32
    gemm_bt128<<<dim3(PD / GBN, M / GBM), 256, 0, stream>>>(
        gated, wout_bf, b_out, b_out, PD, out, PD, out, PD, PD);
}

// Round 3
// 344.220 us; speedup vs baseline: 1.4028x; 1.4028x over previous
//
#include <hip/hip_runtime.h>
#include <hip/hip_bf16.h>

// Problem constants
#define PB 4
#define PN 2048
#define PD 1024
#define PH 16
#define PHD 64
#define NSC 11

typedef __attribute__((ext_vector_type(8))) short short8;
typedef __attribute__((ext_vector_type(4))) float floatx4;

#define AS1 __attribute__((address_space(1)))
#define AS3 __attribute__((address_space(3)))

static __device__ __forceinline__ unsigned short bf16bits(float f) {
    __hip_bfloat16 h = __float2bfloat16(f);
    return __builtin_bit_cast(unsigned short, h);
}

// ---------------- cast kernels ----------------
__global__ void cast_f32_to_bf16_v4(const float4* __restrict__ in,
                                    ushort4* __restrict__ out, int n4) {
    int i = blockIdx.x * blockDim.x + threadIdx.x;
    if (i < n4) {
        float4 v = in[i];
        ushort4 o;
        o.x = bf16bits(v.x);
        o.y = bf16bits(v.y);
        o.z = bf16bits(v.z);
        o.w = bf16bits(v.w);
        out[i] = o;
    }
}

// casts W_qkv (3M) + W_gate (1M) into wcomb, W_out (1M) into wout
__global__ void cast_weights(const float4* __restrict__ wqkv,
                             const float4* __restrict__ wgate,
                             const float4* __restrict__ wout,
                             ushort4* __restrict__ wcomb,
                             ushort4* __restrict__ woutb) {
    int i = blockIdx.x * blockDim.x + threadIdx.x;  // 0 .. 5M/4
    const int QKV4 = 3 * PD * PD / 4;
    const int G4 = PD * PD / 4;
    float4 v;
    ushort4* dst;
    if (i < QKV4) {
        v = wqkv[i];
        dst = wcomb + i;
    } else if (i < QKV4 + G4) {
        v = wgate[i - QKV4];
        dst = wcomb + i;
    } else {
        v = wout[i - QKV4 - G4];
        dst = woutb + (i - QKV4 - G4);
    }
    ushort4 o;
    o.x = bf16bits(v.x);
    o.y = bf16bits(v.y);
    o.z = bf16bits(v.z);
    o.w = bf16bits(v.w);
    *dst = o;
}

// gated = bf16(att * sigmoid(gatep)) — pure HBM stream
__global__ void gate_mul(const float4* __restrict__ att,
                         const float4* __restrict__ gatep,
                         ushort4* __restrict__ gated, int n4) {
    int i = blockIdx.x * blockDim.x + threadIdx.x;
    if (i < n4) {
        float4 a = att[i];
        float4 gp = gatep[i];
        ushort4 o;
        o.x = bf16bits(a.x / (1.f + __expf(-gp.x)));
        o.y = bf16bits(a.y / (1.f + __expf(-gp.y)));
        o.z = bf16bits(a.z / (1.f + __expf(-gp.z)));
        o.w = bf16bits(a.w / (1.f + __expf(-gp.w)));
        gated[i] = o;
    }
}

// ---------------- GEMM 128x128: C = A @ B^T + bias, dual output ----------------
// A: [M,K] bf16 row-major; Bm: [Nn,K] bf16 row-major (W[out][in]).
// Columns < split  -> out1 (row stride N1), bias b1
// Columns >= split -> out2 (row stride N2), bias b2   (split is 128-aligned,
// so the branch is block-uniform)
#define GBM 128
#define GBN 128
#define GBK 64

__global__ __launch_bounds__(256) void gemm_bt128(
    const __hip_bfloat16* __restrict__ A,
    const __hip_bfloat16* __restrict__ Bm,
    const float* __restrict__ b1,
    const float* __restrict__ b2,
    int split,
    float* __restrict__ out1, int N1,
    float* __restrict__ out2, int N2,
    int K) {
    __shared__ alignas(16) __hip_bfloat16 sA[GBM * GBK];
    __shared__ alignas(16) __hip_bfloat16 sB[GBN * GBK];

    const int tid = threadIdx.x;
    const int lane = tid & 63;
    const int wave = tid >> 6;   // 0..3
    const int wy = wave >> 1;    // 0..1
    const int wx = wave & 1;     // 0..1

    // staging: each global_load_lds covers 8 rows x 64 elems (1 KiB)
    const int lrow8 = lane >> 3;                 // 0..7
    const int lchunk = lane & 7;                 // LDS chunk slot (8 elems)
    const int gchunk = lchunk ^ lrow8;           // global chunk fetched into slot

    const int r16 = lane & 15;
    const int qd = lane >> 4;
    const int sw = r16 & 7;  // reader swizzle key

    floatx4 acc[4][4];
#pragma unroll
    for (int i = 0; i < 4; i++)
#pragma unroll
        for (int j = 0; j < 4; j++) acc[i][j] = (floatx4){0.f, 0.f, 0.f, 0.f};

    const size_t arow0 = (size_t)blockIdx.y * GBM;
    const size_t brow0 = (size_t)blockIdx.x * GBN;

    for (int k0 = 0; k0 < K; k0 += GBK) {
        __syncthreads();  // previous ds_reads done before overwrite
#pragma unroll
        for (int half = 0; half < 4; half++) {
            const int rbase = wave * 8 + half * 32;  // wave-uniform
            const __hip_bfloat16* gA =
                A + (arow0 + rbase + lrow8) * K + k0 + gchunk * 8;
            __builtin_amdgcn_global_load_lds(
                (const AS1 unsigned int*)(const void*)gA,
                (AS3 unsigned int*)(void*)(sA + rbase * GBK), 16, 0, 0);
            const __hip_bfloat16* gB =
                Bm + (brow0 + rbase + lrow8) * K + k0 + gchunk * 8;
            __builtin_amdgcn_global_load_lds(
                (const AS1 unsigned int*)(const void*)gB,
                (AS3 unsigned int*)(void*)(sB + rbase * GBK), 16, 0, 0);
        }
        __syncthreads();  // drain staging

#pragma unroll
        for (int kk = 0; kk < 2; kk++) {
            short8 af[4], bf[4];
            const int cs = (qd + 4 * kk);
#pragma unroll
            for (int i = 0; i < 4; i++)
                af[i] = *(const short8*)(sA + (wy * 64 + i * 16 + r16) * GBK +
                                         ((cs ^ sw) * 8));
#pragma unroll
            for (int j = 0; j < 4; j++)
                bf[j] = *(const short8*)(sB + (wx * 64 + j * 16 + r16) * GBK +
                                         ((cs ^ sw) * 8));
#pragma unroll
            for (int i = 0; i < 4; i++)
#pragma unroll
                for (int j = 0; j < 4; j++)
                    acc[i][j] = __builtin_amdgcn_mfma_f32_16x16x32_bf16(
                        af[i], bf[j], acc[i][j], 0, 0, 0);
        }
    }

#pragma unroll
    for (int i = 0; i < 4; i++) {
#pragma unroll
        for (int j = 0; j < 4; j++) {
            const int colb = (int)brow0 + wx * 64 + j * 16 + r16;
            const bool first = colb < split;
            const float bb = first ? b1[colb] : b2[colb - split];
            float* dst = first ? out1 : out2;
            const int nn = first ? N1 : N2;
            const int cc = first ? colb : colb - split;
#pragma unroll
            for (int e = 0; e < 4; e++) {
                const size_t row = arow0 + wy * 64 + i * 16 + qd * 4 + e;
                dst[row * (size_t)nn + cc] = acc[i][j][e] + bb;
            }
        }
    }
}

// ---------------- attention kernel (8 lanes / position, float8 per lane) ----
// Layout: 1 wave = 8 consecutive n positions; 8 lanes x float8 per position.
// qkv: [B, N, 3D] fp32 (q | k | v chunks of D); att: [B, N, D] fp32.
// R1 lesson: VGPR 128 -> 4 waves/EU, latency-bound (VALUBusy 44%).
// R2 lesson: forcing 5 waves/EU via __launch_bounds__(256,5) made the
// allocator SPILL the unrolled 21-tap working set (VGPR "48" + 250 MB scratch
// writes, 2.5x slower). Natural allocation only; WRITE_SIZE is the tripwire.
// Body keeps R2's algebraic cuts: offset-0 taps + bypass collapsed to one
// summed weight (96->8 FMAs), dual-user weights combined before the v-FMA,
// pure-DPP red8 (no LDS pipe in the dependence chain).

static constexpr int OFFS[21] = {1, 2, 3, 4, 6, 8, 12, 16, 24, 32, 48,
                                 64, 96, 128, 192, 256, 384, 512, 768, 1024, 1536};
static constexpr int U1J[21] = {0, 0, 0, 1, 1, 2, 2, 3, 3, 4, 4,
                                5, 5, 6, 6, 7, 7, 8, 8, 9, 9};
static constexpr int U1T[21] = {1, 2, 3, 2, 3, 2, 3, 2, 3, 2, 3,
                                2, 3, 2, 3, 2, 3, 2, 3, 2, 3};
// second user j (tau is always 1); -1 = none
static constexpr int U2J[21] = {-1, 1, -1, 2, -1, 3, -1, 4, -1, 5, -1,
                                6, -1, 7, -1, 8, -1, 9, -1, 10, -1};

static __device__ __forceinline__ float red8(float s) {
    // sum across each 8-lane group; all 8 lanes get the sum.
    // Pure-DPP chain: xor1, xor2 butterflies then row_half_mirror.
    int t;
    // quad_perm [1,0,3,2] : lane ^ 1
    t = __builtin_amdgcn_update_dpp(0, __builtin_bit_cast(int, s), 0xB1, 0xF, 0xF, true);
    s += __builtin_bit_cast(float, t);
    // quad_perm [2,3,0,1] : lane ^ 2
    t = __builtin_amdgcn_update_dpp(0, __builtin_bit_cast(int, s), 0x4E, 0xF, 0xF, true);
    s += __builtin_bit_cast(float, t);
    // row_half_mirror : lane i <-> 7-i (within 8-lane half-row)
    t = __builtin_amdgcn_update_dpp(0, __builtin_bit_cast(int, s), 0x141, 0xF, 0xF, true);
    s += __builtin_bit_cast(float, t);
    return s;
}

__global__ __launch_bounds__(256) void attn_kernel(
    const float* __restrict__ qkv,
    const float* __restrict__ scale_gain,       // [11,16]
    const float* __restrict__ W_qscale,         // [11,64]
    const float* __restrict__ identity_bypass,  // [16]
    const float* __restrict__ pos_bias,         // [44,16]
    float* __restrict__ att) {
    const int lane = threadIdx.x & 63;
    const int p = lane >> 3;   // position within wave, 0..7
    const int l = lane & 7;    // d-chunk (8 floats), 0..7

    const int flat = (blockIdx.x * 4 + (threadIdx.x >> 6)) * 8;  // first n of wave
    const int n = (flat & (PN - 1)) + p;
    const int h = (flat >> 11) & (PH - 1);
    const int b = flat >> 15;

    const size_t base_bn = (size_t)b * PN;
    const int col = h * PHD + l * 8;

    const float* qp = qkv + (base_bn + n) * (3 * PD) + col;
    const float4 qa = *(const float4*)qp;
    const float4 qb = *(const float4*)(qp + 4);
    const float4 k0a = *(const float4*)(qp + PD);
    const float4 k0b = *(const float4*)(qp + PD + 4);
    const float4 v0a = *(const float4*)(qp + 2 * PD);
    const float4 v0b = *(const float4*)(qp + 2 * PD + 4);

    auto dot8 = [](float4 a0, float4 a1, float4 b0, float4 b1) {
        float s = a0.x * b0.x;
        s = fmaf(a0.y, b0.y, s);
        s = fmaf(a0.z, b0.z, s);
        s = fmaf(a0.w, b0.w, s);
        s = fmaf(a1.x, b1.x, s);
        s = fmaf(a1.y, b1.y, s);
        s = fmaf(a1.z, b1.z, s);
        s = fmaf(a1.w, b1.w, s);
        return red8(s);
    };

    const float dot0 = dot8(qa, qb, k0a, k0b);  // k0 regs die here

    // gains = softmax(q @ W_qscale^T + scale_gain[:,h]) over 11 scales
    float g[NSC];
    float mx = -1e30f;
#pragma unroll
    for (int s = 0; s < NSC; s++) {
        const float* wp = W_qscale + s * PHD + l * 8;
        const float4 w0 = *(const float4*)wp;
        const float4 w1 = *(const float4*)(wp + 4);
        g[s] = dot8(qa, qb, w0, w1) + scale_gain[s * PH + h];
        mx = fmaxf(mx, g[s]);
    }
    float ssum = 0.f;
#pragma unroll
    for (int s = 0; s < NSC; s++) {
        g[s] = __expf(g[s] - mx);
        ssum += g[s];
    }
    const float inv = 1.f / ssum;
#pragma unroll
    for (int s = 0; s < NSC; s++) g[s] *= inv;

    const float D4c[4] = {0.4829629131445341f, 0.8365163037378079f,
                          0.2241438680420134f, -0.1294095225512604f};

    float4 o0, o1;
    float z;

    // ---- offset-0 block: 11 tau=0 taps + identity bypass, all scale v0.
    // Sum the 12 scalar weights first, then ONE 8-wide FMA pass.
    // All terms positive (coef0>0, feat>=0, g>=0, bp>=0) so z gets the same sum.
    {
        const float bp = log1pf(__expf(identity_bypass[h]));  // softplus
        const float f0 = (dot0 > 0.f ? dot0 : __expf(dot0) - 1.f) + 1.f;
        float wsum = bp * f0;
#pragma unroll
        for (int j = 0; j < NSC; j++) {
            const float xx = dot0 + pos_bias[(j * 4) * PH + h];
            const float feat = (xx > 0.f ? xx : __expf(xx) - 1.f) + 1.f;
            wsum = fmaf(g[j], D4c[0] * feat, wsum);
        }
        z = wsum;
        o0.x = wsum * v0a.x;
        o0.y = wsum * v0a.y;
        o0.z = wsum * v0a.z;
        o0.w = wsum * v0a.w;
        o1.x = wsum * v0b.x;
        o1.y = wsum * v0b.y;
        o1.z = wsum * v0b.z;
        o1.w = wsum * v0b.w;
    }  // v0 regs die here

    // ---- distinct nonzero offsets (each used by 1-2 taps, sharing k/v rows)
    // Masking: dv *= vm (padded rows dot to 0, matching reference zero-pad);
    // the combined out-weight is masked, v is NOT; z is UNmasked (reference
    // accumulates qk_feat for padded rows too).
#pragma unroll
    for (int t = 0; t < 21; t++) {
        const int off = OFFS[t];
        const bool valid = (n >= off);
        const int idx = valid ? (n - off) : 0;
        const float vm = valid ? 1.f : 0.f;
        const size_t rb = (base_bn + idx) * (3 * PD);
        const float* kp = qkv + rb + PD + col;
        const float* vp = qkv + rb + 2 * PD + col;
        const float4 k4a = *(const float4*)kp;
        const float4 k4b = *(const float4*)(kp + 4);
        const float4 v4a = *(const float4*)vp;
        const float4 v4b = *(const float4*)(vp + 4);
        const float dv = dot8(qa, qb, k4a, k4b) * vm;

        // user 1: (U1J[t], U1T[t])
        float wv, zacc;
        {
            const int j = U1J[t], tau = U1T[t];
            const float xx = dv + pos_bias[(j * 4 + tau) * PH + h];
            const float feat = (xx > 0.f ? xx : __expf(xx) - 1.f) + 1.f;
            const float wp = g[j] * (D4c[tau] * feat);
            zacc = fabsf(wp);  // = g * |coef| * feat  (g,feat >= 0)
            wv = wp;
        }
        // user 2: (U2J[t], tau=1) if present
        if (U2J[t] >= 0) {
            const int j = U2J[t];
            const float xx = dv + pos_bias[(j * 4 + 1) * PH + h];
            const float feat = (xx > 0.f ? xx : __expf(xx) - 1.f) + 1.f;
            const float wp = g[j] * (D4c[1] * feat);
            zacc += wp;  // coef > 0
            wv += wp;
        }
        z += zacc;
        wv *= vm;
        o0.x = fmaf(wv, v4a.x, o0.x);
        o0.y = fmaf(wv, v4a.y, o0.y);
        o0.z = fmaf(wv, v4a.z, o0.z);
        o0.w = fmaf(wv, v4a.w, o0.w);
        o1.x = fmaf(wv, v4b.x, o1.x);
        o1.y = fmaf(wv, v4b.y, o1.y);
        o1.z = fmaf(wv, v4b.z, o1.z);
        o1.w = fmaf(wv, v4b.w, o1.w);
    }

    const float zi = 1.f / (z + 1e-6f);
    float4 r0, r1;
    r0.x = o0.x * zi; r0.y = o0.y * zi; r0.z = o0.z * zi; r0.w = o0.w * zi;
    r1.x = o1.x * zi; r1.y = o1.y * zi; r1.z = o1.z * zi; r1.w = o1.w * zi;
    float* op = att + (base_bn + n) * PD + col;
    *(float4*)op = r0;
    *(float4*)(op + 4) = r1;
}

// ---------------- launch ----------------
extern "C" void kernel_launch(void* const* d_in, const int* in_sizes, int n_in,
                              void* d_out, int out_size, void* d_ws, size_t ws_size,
                              hipStream_t stream) {
    const float* x = (const float*)d_in[0];
    const float* W_qkv = (const float*)d_in[1];
    const float* b_qkv = (const float*)d_in[2];
    const float* W_out = (const float*)d_in[3];
    const float* b_out = (const float*)d_in[4];
    const float* W_gate = (const float*)d_in[5];
    const float* b_gate = (const float*)d_in[6];
    const float* scale_gain = (const float*)d_in[7];
    const float* W_qscale = (const float*)d_in[8];
    const float* identity_bypass = (const float*)d_in[9];
    const float* pos_bias = (const float*)d_in[10];
    float* out = (float*)d_out;

    const int M = PB * PN;  // 8192
    char* ws = (char*)d_ws;
    size_t off = 0;
    auto alloc = [&](size_t bytes) -> void* {
        void* p = ws + off;
        off += (bytes + 255) & ~(size_t)255;
        return p;
    };
    __hip_bfloat16* x_bf = (__hip_bfloat16*)alloc((size_t)M * PD * 2);
    __hip_bfloat16* wcomb_bf = (__hip_bfloat16*)alloc((size_t)4 * PD * PD * 2);
    __hip_bfloat16* wout_bf = (__hip_bfloat16*)alloc((size_t)PD * PD * 2);
    float* qkv = (float*)alloc((size_t)M * 3 * PD * 4);
    float* gate = (float*)alloc((size_t)M * PD * 4);
    float* att = (float*)alloc((size_t)M * PD * 4);
    __hip_bfloat16* gated = (__hip_bfloat16*)alloc((size_t)M * PD * 2);

    // casts
    cast_f32_to_bf16_v4<<<(M * PD / 4) / 256, 256, 0, stream>>>(
        (const float4*)x, (ushort4*)x_bf, M * PD / 4);
    cast_weights<<<(5 * PD * PD / 4) / 256, 256, 0, stream>>>(
        (const float4*)W_qkv, (const float4*)W_gate, (const float4*)W_out,
        (ushort4*)wcomb_bf, (ushort4*)wout_bf);

    // {qkv, gate} = x @ [W_qkv; W_gate]^T + {b_qkv, b_gate}
    gemm_bt128<<<dim3(4 * PD / GBN, M / GBM), 256, 0, stream>>>(
        x_bf, wcomb_bf, b_qkv, b_gate, 3 * PD, qkv, 3 * PD, gate, PD, PD);

    // attention -> att fp32 [8192, 1024]   (8 positions per wave, 32 per block)
    attn_kernel<<<(PB * PH * PN) / 32, 256, 0, stream>>>(
        qkv, scale_gain, W_qscale, identity_bypass, pos_bias, att);

    // gated = bf16(att * sigmoid(gate))  (elementwise, HBM-bound ~12 us)
    gate_mul<<<(M * PD / 4) / 256, 256, 0, stream>>>(
        (const float4*)att, (const float4*)gate, (ushort4*)gated, M * PD / 4);

    // out = gated @ W_out^T + b_out  -> fp32
    gemm_bt128<<<dim3(PD / GBN, M / GBM), 256, 0, stream>>>(
        gated, wout_bf, b_out, b_out, PD, out, PD, out, PD, PD);
}

// Round 4
// 328.405 us; speedup vs baseline: 1.4704x; 1.0482x over previous
//
#include <hip/hip_runtime.h>
#include <hip/hip_bf16.h>

// Problem constants
#define PB 4
#define PN 2048
#define PD 1024
#define PH 16
#define PHD 64
#define NSC 11

typedef __attribute__((ext_vector_type(8))) short short8;
typedef __attribute__((ext_vector_type(4))) float floatx4;

#define AS1 __attribute__((address_space(1)))
#define AS3 __attribute__((address_space(3)))

static __device__ __forceinline__ unsigned short bf16bits(float f) {
    __hip_bfloat16 h = __float2bfloat16(f);
    return __builtin_bit_cast(unsigned short, h);
}

// ---------------- cast kernels ----------------
__global__ void cast_f32_to_bf16_v4(const float4* __restrict__ in,
                                    ushort4* __restrict__ out, int n4) {
    int i = blockIdx.x * blockDim.x + threadIdx.x;
    if (i < n4) {
        float4 v = in[i];
        ushort4 o;
        o.x = bf16bits(v.x);
        o.y = bf16bits(v.y);
        o.z = bf16bits(v.z);
        o.w = bf16bits(v.w);
        out[i] = o;
    }
}

// casts W_qkv (3M) + W_gate (1M) into wcomb, W_out (1M) into wout
__global__ void cast_weights(const float4* __restrict__ wqkv,
                             const float4* __restrict__ wgate,
                             const float4* __restrict__ wout,
                             ushort4* __restrict__ wcomb,
                             ushort4* __restrict__ woutb) {
    int i = blockIdx.x * blockDim.x + threadIdx.x;  // 0 .. 5M/4
    const int QKV4 = 3 * PD * PD / 4;
    const int G4 = PD * PD / 4;
    float4 v;
    ushort4* dst;
    if (i < QKV4) {
        v = wqkv[i];
        dst = wcomb + i;
    } else if (i < QKV4 + G4) {
        v = wgate[i - QKV4];
        dst = wcomb + i;
    } else {
        v = wout[i - QKV4 - G4];
        dst = woutb + (i - QKV4 - G4);
    }
    ushort4 o;
    o.x = bf16bits(v.x);
    o.y = bf16bits(v.y);
    o.z = bf16bits(v.z);
    o.w = bf16bits(v.w);
    *dst = o;
}

// gated = bf16(att * sigmoid(gatep)) — pure HBM stream
__global__ void gate_mul(const float4* __restrict__ att,
                         const float4* __restrict__ gatep,
                         ushort4* __restrict__ gated, int n4) {
    int i = blockIdx.x * blockDim.x + threadIdx.x;
    if (i < n4) {
        float4 a = att[i];
        float4 gp = gatep[i];
        ushort4 o;
        o.x = bf16bits(a.x / (1.f + __expf(-gp.x)));
        o.y = bf16bits(a.y / (1.f + __expf(-gp.y)));
        o.z = bf16bits(a.z / (1.f + __expf(-gp.z)));
        o.w = bf16bits(a.w / (1.f + __expf(-gp.w)));
        gated[i] = o;
    }
}

// ---------------- GEMM 128x128: C = A @ B^T + bias, dual output ----------------
// A: [M,K] bf16 row-major; Bm: [Nn,K] bf16 row-major (W[out][in]).
// Columns < split  -> out1 (row stride N1), bias b1
// Columns >= split -> out2 (row stride N2), bias b2   (split is 128-aligned,
// so the branch is block-uniform)
#define GBM 128
#define GBN 128
#define GBK 64

__global__ __launch_bounds__(256) void gemm_bt128(
    const __hip_bfloat16* __restrict__ A,
    const __hip_bfloat16* __restrict__ Bm,
    const float* __restrict__ b1,
    const float* __restrict__ b2,
    int split,
    float* __restrict__ out1, int N1,
    float* __restrict__ out2, int N2,
    int K) {
    __shared__ alignas(16) __hip_bfloat16 sA[GBM * GBK];
    __shared__ alignas(16) __hip_bfloat16 sB[GBN * GBK];

    const int tid = threadIdx.x;
    const int lane = tid & 63;
    const int wave = tid >> 6;   // 0..3
    const int wy = wave >> 1;    // 0..1
    const int wx = wave & 1;     // 0..1

    // staging: each global_load_lds covers 8 rows x 64 elems (1 KiB)
    const int lrow8 = lane >> 3;                 // 0..7
    const int lchunk = lane & 7;                 // LDS chunk slot (8 elems)
    const int gchunk = lchunk ^ lrow8;           // global chunk fetched into slot

    const int r16 = lane & 15;
    const int qd = lane >> 4;
    const int sw = r16 & 7;  // reader swizzle key

    floatx4 acc[4][4];
#pragma unroll
    for (int i = 0; i < 4; i++)
#pragma unroll
        for (int j = 0; j < 4; j++) acc[i][j] = (floatx4){0.f, 0.f, 0.f, 0.f};

    const size_t arow0 = (size_t)blockIdx.y * GBM;
    const size_t brow0 = (size_t)blockIdx.x * GBN;

    for (int k0 = 0; k0 < K; k0 += GBK) {
        __syncthreads();  // previous ds_reads done before overwrite
#pragma unroll
        for (int half = 0; half < 4; half++) {
            const int rbase = wave * 8 + half * 32;  // wave-uniform
            const __hip_bfloat16* gA =
                A + (arow0 + rbase + lrow8) * K + k0 + gchunk * 8;
            __builtin_amdgcn_global_load_lds(
                (const AS1 unsigned int*)(const void*)gA,
                (AS3 unsigned int*)(void*)(sA + rbase * GBK), 16, 0, 0);
            const __hip_bfloat16* gB =
                Bm + (brow0 + rbase + lrow8) * K + k0 + gchunk * 8;
            __builtin_amdgcn_global_load_lds(
                (const AS1 unsigned int*)(const void*)gB,
                (AS3 unsigned int*)(void*)(sB + rbase * GBK), 16, 0, 0);
        }
        __syncthreads();  // drain staging

#pragma unroll
        for (int kk = 0; kk < 2; kk++) {
            short8 af[4], bf[4];
            const int cs = (qd + 4 * kk);
#pragma unroll
            for (int i = 0; i < 4; i++)
                af[i] = *(const short8*)(sA + (wy * 64 + i * 16 + r16) * GBK +
                                         ((cs ^ sw) * 8));
#pragma unroll
            for (int j = 0; j < 4; j++)
                bf[j] = *(const short8*)(sB + (wx * 64 + j * 16 + r16) * GBK +
                                         ((cs ^ sw) * 8));
#pragma unroll
            for (int i = 0; i < 4; i++)
#pragma unroll
                for (int j = 0; j < 4; j++)
                    acc[i][j] = __builtin_amdgcn_mfma_f32_16x16x32_bf16(
                        af[i], bf[j], acc[i][j], 0, 0, 0);
        }
    }

#pragma unroll
    for (int i = 0; i < 4; i++) {
#pragma unroll
        for (int j = 0; j < 4; j++) {
            const int colb = (int)brow0 + wx * 64 + j * 16 + r16;
            const bool first = colb < split;
            const float bb = first ? b1[colb] : b2[colb - split];
            float* dst = first ? out1 : out2;
            const int nn = first ? N1 : N2;
            const int cc = first ? colb : colb - split;
#pragma unroll
            for (int e = 0; e < 4; e++) {
                const size_t row = arow0 + wy * 64 + i * 16 + qd * 4 + e;
                dst[row * (size_t)nn + cc] = acc[i][j][e] + bb;
            }
        }
    }
}

// ---------------- attention kernel (8 lanes / position, float8 per lane) ----
// Layout: 1 wave = 8 consecutive n positions; 8 lanes x float8 per position.
// qkv: [B, N, 3D] fp32 (q | k | v chunks of D); att: [B, N, D] fp32.
// R1 lesson: VGPR 128 -> 4 waves/EU, latency-bound (VALUBusy 44%).
// R2 lesson: forcing 5 waves/EU spilled (250 MB scratch, 2.5x slower).
// R3 lesson: algebraic cuts landed (busy 43->39 us) but dur got WORSE
// (96->106) and FETCH rose to 249 MB (~2x the unique footprint). The stall
// source is k/v tap reads missing L2: consecutive n-strips (whose rows the
// taps reach back into) round-robin across XCDs, and per-XCD L2s don't share.
// R4: XCD-chunked block swizzle — XCD x gets a contiguous run of 512 strips
// (8 whole (b,h) slices, n-ordered), so offset reach-back rows live in the
// SAME XCD's L2. Bijective since 4096 % 8 == 0.

static constexpr int OFFS[21] = {1, 2, 3, 4, 6, 8, 12, 16, 24, 32, 48,
                                 64, 96, 128, 192, 256, 384, 512, 768, 1024, 1536};
static constexpr int U1J[21] = {0, 0, 0, 1, 1, 2, 2, 3, 3, 4, 4,
                                5, 5, 6, 6, 7, 7, 8, 8, 9, 9};
static constexpr int U1T[21] = {1, 2, 3, 2, 3, 2, 3, 2, 3, 2, 3,
                                2, 3, 2, 3, 2, 3, 2, 3, 2, 3};
// second user j (tau is always 1); -1 = none
static constexpr int U2J[21] = {-1, 1, -1, 2, -1, 3, -1, 4, -1, 5, -1,
                                6, -1, 7, -1, 8, -1, 9, -1, 10, -1};

static __device__ __forceinline__ float red8(float s) {
    // sum across each 8-lane group; all 8 lanes get the sum.
    // Pure-DPP chain: xor1, xor2 butterflies then row_half_mirror.
    int t;
    // quad_perm [1,0,3,2] : lane ^ 1
    t = __builtin_amdgcn_update_dpp(0, __builtin_bit_cast(int, s), 0xB1, 0xF, 0xF, true);
    s += __builtin_bit_cast(float, t);
    // quad_perm [2,3,0,1] : lane ^ 2
    t = __builtin_amdgcn_update_dpp(0, __builtin_bit_cast(int, s), 0x4E, 0xF, 0xF, true);
    s += __builtin_bit_cast(float, t);
    // row_half_mirror : lane i <-> 7-i (within 8-lane half-row)
    t = __builtin_amdgcn_update_dpp(0, __builtin_bit_cast(int, s), 0x141, 0xF, 0xF, true);
    s += __builtin_bit_cast(float, t);
    return s;
}

__global__ __launch_bounds__(256) void attn_kernel(
    const float* __restrict__ qkv,
    const float* __restrict__ scale_gain,       // [11,16]
    const float* __restrict__ W_qscale,         // [11,64]
    const float* __restrict__ identity_bypass,  // [16]
    const float* __restrict__ pos_bias,         // [44,16]
    float* __restrict__ att) {
    const int lane = threadIdx.x & 63;
    const int p = lane >> 3;   // position within wave, 0..7
    const int l = lane & 7;    // d-chunk (8 floats), 0..7

    // XCD-chunked swizzle: hw assigns block i -> XCD i%8; give XCD x the
    // contiguous strip range [x*512, (x+1)*512) so tap reach-back rows stay
    // in its own L2. grid = 4096 blocks (fixed), 4096 % 8 == 0 -> bijective.
    const int wg = blockIdx.x;
    const int swg = (wg & 7) * 512 + (wg >> 3);

    const int flat = (swg * 4 + (threadIdx.x >> 6)) * 8;  // first n of wave
    const int n = (flat & (PN - 1)) + p;
    const int h = (flat >> 11) & (PH - 1);
    const int b = flat >> 15;

    const size_t base_bn = (size_t)b * PN;
    const int col = h * PHD + l * 8;

    const float* qp = qkv + (base_bn + n) * (3 * PD) + col;
    const float4 qa = *(const float4*)qp;
    const float4 qb = *(const float4*)(qp + 4);
    const float4 k0a = *(const float4*)(qp + PD);
    const float4 k0b = *(const float4*)(qp + PD + 4);
    const float4 v0a = *(const float4*)(qp + 2 * PD);
    const float4 v0b = *(const float4*)(qp + 2 * PD + 4);

    auto dot8 = [](float4 a0, float4 a1, float4 b0, float4 b1) {
        float s = a0.x * b0.x;
        s = fmaf(a0.y, b0.y, s);
        s = fmaf(a0.z, b0.z, s);
        s = fmaf(a0.w, b0.w, s);
        s = fmaf(a1.x, b1.x, s);
        s = fmaf(a1.y, b1.y, s);
        s = fmaf(a1.z, b1.z, s);
        s = fmaf(a1.w, b1.w, s);
        return red8(s);
    };

    const float dot0 = dot8(qa, qb, k0a, k0b);  // k0 regs die here

    // gains = softmax(q @ W_qscale^T + scale_gain[:,h]) over 11 scales
    float g[NSC];
    float mx = -1e30f;
#pragma unroll
    for (int s = 0; s < NSC; s++) {
        const float* wp = W_qscale + s * PHD + l * 8;
        const float4 w0 = *(const float4*)wp;
        const float4 w1 = *(const float4*)(wp + 4);
        g[s] = dot8(qa, qb, w0, w1) + scale_gain[s * PH + h];
        mx = fmaxf(mx, g[s]);
    }
    float ssum = 0.f;
#pragma unroll
    for (int s = 0; s < NSC; s++) {
        g[s] = __expf(g[s] - mx);
        ssum += g[s];
    }
    const float inv = 1.f / ssum;
#pragma unroll
    for (int s = 0; s < NSC; s++) g[s] *= inv;

    const float D4c[4] = {0.4829629131445341f, 0.8365163037378079f,
                          0.2241438680420134f, -0.1294095225512604f};

    float4 o0, o1;
    float z;

    // ---- offset-0 block: 11 tau=0 taps + identity bypass, all scale v0.
    // Sum the 12 scalar weights first, then ONE 8-wide FMA pass.
    // All terms positive (coef0>0, feat>=0, g>=0, bp>=0) so z gets the same sum.
    {
        const float bp = log1pf(__expf(identity_bypass[h]));  // softplus
        const float f0 = (dot0 > 0.f ? dot0 : __expf(dot0) - 1.f) + 1.f;
        float wsum = bp * f0;
#pragma unroll
        for (int j = 0; j < NSC; j++) {
            const float xx = dot0 + pos_bias[(j * 4) * PH + h];
            const float feat = (xx > 0.f ? xx : __expf(xx) - 1.f) + 1.f;
            wsum = fmaf(g[j], D4c[0] * feat, wsum);
        }
        z = wsum;
        o0.x = wsum * v0a.x;
        o0.y = wsum * v0a.y;
        o0.z = wsum * v0a.z;
        o0.w = wsum * v0a.w;
        o1.x = wsum * v0b.x;
        o1.y = wsum * v0b.y;
        o1.z = wsum * v0b.z;
        o1.w = wsum * v0b.w;
    }  // v0 regs die here

    // ---- distinct nonzero offsets (each used by 1-2 taps, sharing k/v rows)
    // Masking: dv *= vm (padded rows dot to 0, matching reference zero-pad);
    // the combined out-weight is masked, v is NOT; z is UNmasked (reference
    // accumulates qk_feat for padded rows too).
#pragma unroll
    for (int t = 0; t < 21; t++) {
        const int off = OFFS[t];
        const bool valid = (n >= off);
        const int idx = valid ? (n - off) : 0;
        const float vm = valid ? 1.f : 0.f;
        const size_t rb = (base_bn + idx) * (3 * PD);
        const float* kp = qkv + rb + PD + col;
        const float* vp = qkv + rb + 2 * PD + col;
        const float4 k4a = *(const float4*)kp;
        const float4 k4b = *(const float4*)(kp + 4);
        const float4 v4a = *(const float4*)vp;
        const float4 v4b = *(const float4*)(vp + 4);
        const float dv = dot8(qa, qb, k4a, k4b) * vm;

        // user 1: (U1J[t], U1T[t])
        float wv, zacc;
        {
            const int j = U1J[t], tau = U1T[t];
            const float xx = dv + pos_bias[(j * 4 + tau) * PH + h];
            const float feat = (xx > 0.f ? xx : __expf(xx) - 1.f) + 1.f;
            const float wp = g[j] * (D4c[tau] * feat);
            zacc = fabsf(wp);  // = g * |coef| * feat  (g,feat >= 0)
            wv = wp;
        }
        // user 2: (U2J[t], tau=1) if present
        if (U2J[t] >= 0) {
            const int j = U2J[t];
            const float xx = dv + pos_bias[(j * 4 + 1) * PH + h];
            const float feat = (xx > 0.f ? xx : __expf(xx) - 1.f) + 1.f;
            const float wp = g[j] * (D4c[1] * feat);
            zacc += wp;  // coef > 0
            wv += wp;
        }
        z += zacc;
        wv *= vm;
        o0.x = fmaf(wv, v4a.x, o0.x);
        o0.y = fmaf(wv, v4a.y, o0.y);
        o0.z = fmaf(wv, v4a.z, o0.z);
        o0.w = fmaf(wv, v4a.w, o0.w);
        o1.x = fmaf(wv, v4b.x, o1.x);
        o1.y = fmaf(wv, v4b.y, o1.y);
        o1.z = fmaf(wv, v4b.z, o1.z);
        o1.w = fmaf(wv, v4b.w, o1.w);
    }

    const float zi = 1.f / (z + 1e-6f);
    float4 r0, r1;
    r0.x = o0.x * zi; r0.y = o0.y * zi; r0.z = o0.z * zi; r0.w = o0.w * zi;
    r1.x = o1.x * zi; r1.y = o1.y * zi; r1.z = o1.z * zi; r1.w = o1.w * zi;
    float* op = att + (base_bn + n) * PD + col;
    *(float4*)op = r0;
    *(float4*)(op + 4) = r1;
}

// ---------------- launch ----------------
extern "C" void kernel_launch(void* const* d_in, const int* in_sizes, int n_in,
                              void* d_out, int out_size, void* d_ws, size_t ws_size,
                              hipStream_t stream) {
    const float* x = (const float*)d_in[0];
    const float* W_qkv = (const float*)d_in[1];
    const float* b_qkv = (const float*)d_in[2];
    const float* W_out = (const float*)d_in[3];
    const float* b_out = (const float*)d_in[4];
    const float* W_gate = (const float*)d_in[5];
    const float* b_gate = (const float*)d_in[6];
    const float* scale_gain = (const float*)d_in[7];
    const float* W_qscale = (const float*)d_in[8];
    const float* identity_bypass = (const float*)d_in[9];
    const float* pos_bias = (const float*)d_in[10];
    float* out = (float*)d_out;

    const int M = PB * PN;  // 8192
    char* ws = (char*)d_ws;
    size_t off = 0;
    auto alloc = [&](size_t bytes) -> void* {
        void* p = ws + off;
        off += (bytes + 255) & ~(size_t)255;
        return p;
    };
    __hip_bfloat16* x_bf = (__hip_bfloat16*)alloc((size_t)M * PD * 2);
    __hip_bfloat16* wcomb_bf = (__hip_bfloat16*)alloc((size_t)4 * PD * PD * 2);
    __hip_bfloat16* wout_bf = (__hip_bfloat16*)alloc((size_t)PD * PD * 2);
    float* qkv = (float*)alloc((size_t)M * 3 * PD * 4);
    float* gate = (float*)alloc((size_t)M * PD * 4);
    float* att = (float*)alloc((size_t)M * PD * 4);
    __hip_bfloat16* gated = (__hip_bfloat16*)alloc((size_t)M * PD * 2);

    // casts
    cast_f32_to_bf16_v4<<<(M * PD / 4) / 256, 256, 0, stream>>>(
        (const float4*)x, (ushort4*)x_bf, M * PD / 4);
    cast_weights<<<(5 * PD * PD / 4) / 256, 256, 0, stream>>>(
        (const float4*)W_qkv, (const float4*)W_gate, (const float4*)W_out,
        (ushort4*)wcomb_bf, (ushort4*)wout_bf);

    // {qkv, gate} = x @ [W_qkv; W_gate]^T + {b_qkv, b_gate}
    gemm_bt128<<<dim3(4 * PD / GBN, M / GBM), 256, 0, stream>>>(
        x_bf, wcomb_bf, b_qkv, b_gate, 3 * PD, qkv, 3 * PD, gate, PD, PD);

    // attention -> att fp32 [8192, 1024]   (8 positions per wave, 32 per block)
    attn_kernel<<<(PB * PH * PN) / 32, 256, 0, stream>>>(
        qkv, scale_gain, W_qscale, identity_bypass, pos_bias, att);

    // gated = bf16(att * sigmoid(gate))  (elementwise, HBM-bound ~12 us)
    gate_mul<<<(M * PD / 4) / 256, 256, 0, stream>>>(
        (const float4*)att, (const float4*)gate, (ushort4*)gated, M * PD / 4);

    // out = gated @ W_out^T + b_out  -> fp32
    gemm_bt128<<<dim3(PD / GBN, M / GBM), 256, 0, stream>>>(
        gated, wout_bf, b_out, b_out, PD, out, PD, out, PD, PD);
}

// Round 5
// 303.913 us; speedup vs baseline: 1.5889x; 1.0806x over previous
//
#include <hip/hip_runtime.h>
#include <hip/hip_bf16.h>

// Problem constants
#define PB 4
#define PN 2048
#define PD 1024
#define PH 16
#define PHD 64
#define NSC 11

typedef __attribute__((ext_vector_type(8))) short short8;
typedef __attribute__((ext_vector_type(4))) float floatx4;

#define AS1 __attribute__((address_space(1)))
#define AS3 __attribute__((address_space(3)))

static __device__ __forceinline__ unsigned short bf16bits(float f) {
    __hip_bfloat16 h = __float2bfloat16(f);
    return __builtin_bit_cast(unsigned short, h);
}

// ---------------- cast kernels ----------------
__global__ void cast_f32_to_bf16_v4(const float4* __restrict__ in,
                                    ushort4* __restrict__ out, int n4) {
    int i = blockIdx.x * blockDim.x + threadIdx.x;
    if (i < n4) {
        float4 v = in[i];
        ushort4 o;
        o.x = bf16bits(v.x);
        o.y = bf16bits(v.y);
        o.z = bf16bits(v.z);
        o.w = bf16bits(v.w);
        out[i] = o;
    }
}

// casts W_qkv (3M) + W_gate (1M) into wcomb, W_out (1M) into wout
__global__ void cast_weights(const float4* __restrict__ wqkv,
                             const float4* __restrict__ wgate,
                             const float4* __restrict__ wout,
                             ushort4* __restrict__ wcomb,
                             ushort4* __restrict__ woutb) {
    int i = blockIdx.x * blockDim.x + threadIdx.x;  // 0 .. 5M/4
    const int QKV4 = 3 * PD * PD / 4;
    const int G4 = PD * PD / 4;
    float4 v;
    ushort4* dst;
    if (i < QKV4) {
        v = wqkv[i];
        dst = wcomb + i;
    } else if (i < QKV4 + G4) {
        v = wgate[i - QKV4];
        dst = wcomb + i;
    } else {
        v = wout[i - QKV4 - G4];
        dst = woutb + (i - QKV4 - G4);
    }
    ushort4 o;
    o.x = bf16bits(v.x);
    o.y = bf16bits(v.y);
    o.z = bf16bits(v.z);
    o.w = bf16bits(v.w);
    *dst = o;
}

// gated = bf16(att * sigmoid(gatep)) — pure HBM stream
__global__ void gate_mul(const float4* __restrict__ att,
                         const float4* __restrict__ gatep,
                         ushort4* __restrict__ gated, int n4) {
    int i = blockIdx.x * blockDim.x + threadIdx.x;
    if (i < n4) {
        float4 a = att[i];
        float4 gp = gatep[i];
        ushort4 o;
        o.x = bf16bits(a.x / (1.f + __expf(-gp.x)));
        o.y = bf16bits(a.y / (1.f + __expf(-gp.y)));
        o.z = bf16bits(a.z / (1.f + __expf(-gp.z)));
        o.w = bf16bits(a.w / (1.f + __expf(-gp.w)));
        gated[i] = o;
    }
}

// ---------------- GEMM 128x128 (kept for gemm2: N=1024 -> 512 blocks) -------
#define GBM 128
#define GBN 128
#define GBK 64

__global__ __launch_bounds__(256) void gemm_bt128(
    const __hip_bfloat16* __restrict__ A,
    const __hip_bfloat16* __restrict__ Bm,
    const float* __restrict__ b1,
    const float* __restrict__ b2,
    int split,
    float* __restrict__ out1, int N1,
    float* __restrict__ out2, int N2,
    int K) {
    __shared__ alignas(16) __hip_bfloat16 sA[GBM * GBK];
    __shared__ alignas(16) __hip_bfloat16 sB[GBN * GBK];

    const int tid = threadIdx.x;
    const int lane = tid & 63;
    const int wave = tid >> 6;   // 0..3
    const int wy = wave >> 1;    // 0..1
    const int wx = wave & 1;     // 0..1

    const int lrow8 = lane >> 3;                 // 0..7
    const int lchunk = lane & 7;                 // LDS chunk slot (8 elems)
    const int gchunk = lchunk ^ lrow8;           // global chunk fetched into slot

    const int r16 = lane & 15;
    const int qd = lane >> 4;
    const int sw = r16 & 7;  // reader swizzle key

    floatx4 acc[4][4];
#pragma unroll
    for (int i = 0; i < 4; i++)
#pragma unroll
        for (int j = 0; j < 4; j++) acc[i][j] = (floatx4){0.f, 0.f, 0.f, 0.f};

    const size_t arow0 = (size_t)blockIdx.y * GBM;
    const size_t brow0 = (size_t)blockIdx.x * GBN;

    for (int k0 = 0; k0 < K; k0 += GBK) {
        __syncthreads();  // previous ds_reads done before overwrite
#pragma unroll
        for (int half = 0; half < 4; half++) {
            const int rbase = wave * 8 + half * 32;  // wave-uniform
            const __hip_bfloat16* gA =
                A + (arow0 + rbase + lrow8) * K + k0 + gchunk * 8;
            __builtin_amdgcn_global_load_lds(
                (const AS1 unsigned int*)(const void*)gA,
                (AS3 unsigned int*)(void*)(sA + rbase * GBK), 16, 0, 0);
            const __hip_bfloat16* gB =
                Bm + (brow0 + rbase + lrow8) * K + k0 + gchunk * 8;
            __builtin_amdgcn_global_load_lds(
                (const AS1 unsigned int*)(const void*)gB,
                (AS3 unsigned int*)(void*)(sB + rbase * GBK), 16, 0, 0);
        }
        __syncthreads();  // drain staging

#pragma unroll
        for (int kk = 0; kk < 2; kk++) {
            short8 af[4], bf[4];
            const int cs = (qd + 4 * kk);
#pragma unroll
            for (int i = 0; i < 4; i++)
                af[i] = *(const short8*)(sA + (wy * 64 + i * 16 + r16) * GBK +
                                         ((cs ^ sw) * 8));
#pragma unroll
            for (int j = 0; j < 4; j++)
                bf[j] = *(const short8*)(sB + (wx * 64 + j * 16 + r16) * GBK +
                                         ((cs ^ sw) * 8));
#pragma unroll
            for (int i = 0; i < 4; i++)
#pragma unroll
                for (int j = 0; j < 4; j++)
                    acc[i][j] = __builtin_amdgcn_mfma_f32_16x16x32_bf16(
                        af[i], bf[j], acc[i][j], 0, 0, 0);
        }
    }

#pragma unroll
    for (int i = 0; i < 4; i++) {
#pragma unroll
        for (int j = 0; j < 4; j++) {
            const int colb = (int)brow0 + wx * 64 + j * 16 + r16;
            const bool first = colb < split;
            const float bb = first ? b1[colb] : b2[colb - split];
            float* dst = first ? out1 : out2;
            const int nn = first ? N1 : N2;
            const int cc = first ? colb : colb - split;
#pragma unroll
            for (int e = 0; e < 4; e++) {
                const size_t row = arow0 + wy * 64 + i * 16 + qd * 4 + e;
                dst[row * (size_t)nn + cc] = acc[i][j][e] + bb;
            }
        }
    }
}

// ---------------- GEMM 256x256, 8 waves, counted-vmcnt schedule (gemm1) ----
// R4 pmc: gemm_bt128 on the qkv GEMM = 636 TF, MfmaUtil 27% — the documented
// 2-barrier-structure ceiling (syncthreads drains vmcnt(0) every K-step).
// This kernel: BM=BN=256, BK=64, 512 thr / 8 waves (2M x 4N), per-wave
// acc[8][4]. Double-buffered LDS (128 KiB), prefetch distance 2 K-tiles:
//   phases A,B : ALL ds_reads of buf[c] (A+B frags cached in regs) + MFMA Q0,Q1
//   lgkmcnt(0); barrier        <- every wave's reads of buf[c] COMPLETE
//   stage kt+2 -> buf[c]       <- overwrite is now race-free
//   phases C,D : pure-register MFMA Q2,Q3 (overlaps stage issue)
//   s_waitcnt vmcnt(8)         <- waits kt+1's loads (issued LAST iter, ~free);
//                                 kt+2's 8 loads stay in flight ACROSS barrier
//   barrier
// Never vmcnt(0) in the main loop. setprio(1) around MFMA clusters.
// Same XOR chunk swizzle + fragment/epilogue mapping as gemm_bt128 (proven).
#define TBM 256
#define TBN 256
#define TBK 64

__global__ __launch_bounds__(512) void gemm_bt256(
    const __hip_bfloat16* __restrict__ A,
    const __hip_bfloat16* __restrict__ Bm,
    const float* __restrict__ b1,
    const float* __restrict__ b2,
    int split,
    float* __restrict__ out1, int N1,
    float* __restrict__ out2, int N2,
    int K) {
    __shared__ alignas(16) __hip_bfloat16 sA[2 * TBM * TBK];  // 64 KiB
    __shared__ alignas(16) __hip_bfloat16 sB[2 * TBN * TBK];  // 64 KiB

    const int tid = threadIdx.x;
    const int lane = tid & 63;
    const int wid = tid >> 6;    // 0..7
    const int wrow = wid >> 2;   // 0..1 : M half (128 rows)
    const int wcol = wid & 3;    // 0..3 : N quarter (64 cols)

    const int lrow8 = lane >> 3;
    const int lchunk = lane & 7;
    const int gchunk = lchunk ^ lrow8;  // write-side chunk swizzle

    const int r16 = lane & 15;
    const int qd = lane >> 4;
    const int sw = r16 & 7;  // read-side swizzle key

    const size_t arow0 = (size_t)blockIdx.y * TBM;
    const size_t brow0 = (size_t)blockIdx.x * TBN;

    const int nt = K >> 6;  // K-tiles
    const size_t rowskip = (size_t)64 * K;

    // per-thread staging pointers (row = wid*8 + lrow8 within each 64-row round)
    const __hip_bfloat16* gA = A + (arow0 + wid * 8 + lrow8) * (size_t)K + gchunk * 8;
    const __hip_bfloat16* gB = Bm + (brow0 + wid * 8 + lrow8) * (size_t)K + gchunk * 8;
    const int ldsAb = wid * 8 * TBK;  // wave-uniform LDS base (elems)

    auto stage = [&](int cc, int ktn) {
#pragma unroll
        for (int rd = 0; rd < 4; ++rd) {
            __builtin_amdgcn_global_load_lds(
                (const AS1 unsigned int*)(const void*)(gA + (size_t)rd * rowskip + ktn * TBK),
                (AS3 unsigned int*)(void*)(sA + cc * (TBM * TBK) + ldsAb + rd * (64 * TBK)),
                16, 0, 0);
            __builtin_amdgcn_global_load_lds(
                (const AS1 unsigned int*)(const void*)(gB + (size_t)rd * rowskip + ktn * TBK),
                (AS3 unsigned int*)(void*)(sB + cc * (TBN * TBK) + ldsAb + rd * (64 * TBK)),
                16, 0, 0);
        }
    };

    floatx4 acc[8][4];
#pragma unroll
    for (int i = 0; i < 8; i++)
#pragma unroll
        for (int j = 0; j < 4; j++) acc[i][j] = (floatx4){0.f, 0.f, 0.f, 0.f};

    // reader offsets (elems): A row = wrow*128 + rf*16 + r16 ; chunk (cs^sw)*8
    const int aofs = (wrow * 128 + r16) * TBK;
    const int bofs = (wcol * 64 + r16) * TBK;
    const int ck0 = ((qd ^ sw) * 8);
    const int ck1 = (((qd + 4) ^ sw) * 8);

    // prologue: stage K-tiles 0 and 1
    stage(0, 0);
    stage(1, 1);
    asm volatile("s_waitcnt vmcnt(8)" ::: "memory");  // K-tile 0 landed
    __builtin_amdgcn_s_barrier();

#pragma unroll 1
    for (int kt = 0; kt < nt; ++kt) {
        const int c = kt & 1;
        const __hip_bfloat16* sAc = sA + c * (TBM * TBK);
        const __hip_bfloat16* sBc = sB + c * (TBN * TBK);

        short8 afr[8][2], bfr[4][2];

        // ---- Phase A: ds_read af rh0 (rf0-3) + bf ch0 (cf0-1); MFMA Q0
#pragma unroll
        for (int f = 0; f < 2; ++f) {
            bfr[f][0] = *(const short8*)(sBc + bofs + f * 1024 + ck0);
            bfr[f][1] = *(const short8*)(sBc + bofs + f * 1024 + ck1);
        }
#pragma unroll
        for (int f = 0; f < 4; ++f) {
            afr[f][0] = *(const short8*)(sAc + aofs + f * 1024 + ck0);
            afr[f][1] = *(const short8*)(sAc + aofs + f * 1024 + ck1);
        }
        __builtin_amdgcn_s_setprio(1);
#pragma unroll
        for (int i = 0; i < 4; ++i)
#pragma unroll
            for (int j = 0; j < 2; ++j)
#pragma unroll
                for (int kk = 0; kk < 2; ++kk)
                    acc[i][j] = __builtin_amdgcn_mfma_f32_16x16x32_bf16(
                        afr[i][kk], bfr[j][kk], acc[i][j], 0, 0, 0);
        __builtin_amdgcn_s_setprio(0);

        // ---- Phase B: ds_read bf ch1 (cf2-3) + af rh1 (rf4-7); MFMA Q1
#pragma unroll
        for (int f = 2; f < 4; ++f) {
            bfr[f][0] = *(const short8*)(sBc + bofs + f * 1024 + ck0);
            bfr[f][1] = *(const short8*)(sBc + bofs + f * 1024 + ck1);
        }
#pragma unroll
        for (int f = 4; f < 8; ++f) {
            afr[f][0] = *(const short8*)(sAc + aofs + f * 1024 + ck0);
            afr[f][1] = *(const short8*)(sAc + aofs + f * 1024 + ck1);
        }
        __builtin_amdgcn_s_setprio(1);
#pragma unroll
        for (int i = 0; i < 4; ++i)
#pragma unroll
            for (int j = 2; j < 4; ++j)
#pragma unroll
            for (int kk = 0; kk < 2; ++kk)
                    acc[i][j] = __builtin_amdgcn_mfma_f32_16x16x32_bf16(
                        afr[i][kk], bfr[j][kk], acc[i][j], 0, 0, 0);
        __builtin_amdgcn_s_setprio(0);

        // ---- boundary 1: all reads of buf[c] complete across the block
        asm volatile("s_waitcnt lgkmcnt(0)" ::: "memory");
        __builtin_amdgcn_sched_barrier(0);
        __builtin_amdgcn_s_barrier();

        // stage kt+2 into buf[c] (now safe to overwrite)
        if (kt + 2 < nt) stage(c, kt + 2);

        // ---- Phase C: pure-register MFMA Q2 (rf4-7 x cf0-1)
        __builtin_amdgcn_s_setprio(1);
#pragma unroll
        for (int i = 4; i < 8; ++i)
#pragma unroll
            for (int j = 0; j < 2; ++j)
#pragma unroll
                for (int kk = 0; kk < 2; ++kk)
                    acc[i][j] = __builtin_amdgcn_mfma_f32_16x16x32_bf16(
                        afr[i][kk], bfr[j][kk], acc[i][j], 0, 0, 0);
        __builtin_amdgcn_s_setprio(0);

        // ---- Phase D: pure-register MFMA Q3 (rf4-7 x cf2-3)
        __builtin_amdgcn_s_setprio(1);
#pragma unroll
        for (int i = 4; i < 8; ++i)
#pragma unroll
            for (int j = 2; j < 4; ++j)
#pragma unroll
                for (int kk = 0; kk < 2; ++kk)
                    acc[i][j] = __builtin_amdgcn_mfma_f32_16x16x32_bf16(
                        afr[i][kk], bfr[j][kk], acc[i][j], 0, 0, 0);
        __builtin_amdgcn_s_setprio(0);

        // ---- boundary 2: kt+1's data landed; kt+2's loads stay in flight
        if (kt + 2 < nt) {
            asm volatile("s_waitcnt vmcnt(8)" ::: "memory");
        } else if (kt + 1 < nt) {
            asm volatile("s_waitcnt vmcnt(0)" ::: "memory");
        }
        if (kt + 1 < nt) __builtin_amdgcn_s_barrier();
    }

    // ---- epilogue (same proven C/D mapping, dual output + bias)
#pragma unroll
    for (int i = 0; i < 8; i++) {
#pragma unroll
        for (int j = 0; j < 4; j++) {
            const int colb = (int)brow0 + wcol * 64 + j * 16 + r16;
            const bool first = colb < split;
            const float bb = first ? b1[colb] : b2[colb - split];
            float* dst = first ? out1 : out2;
            const int nn = first ? N1 : N2;
            const int cc = first ? colb : colb - split;
#pragma unroll
            for (int e = 0; e < 4; e++) {
                const size_t row = arow0 + wrow * 128 + i * 16 + qd * 4 + e;
                dst[row * (size_t)nn + cc] = acc[i][j][e] + bb;
            }
        }
    }
}

// ---------------- attention kernel (8 lanes / position, float8 per lane) ----
// R4: XCD-chunked block swizzle fixed the k/v L2-miss stall; attn left top-5.

static constexpr int OFFS[21] = {1, 2, 3, 4, 6, 8, 12, 16, 24, 32, 48,
                                 64, 96, 128, 192, 256, 384, 512, 768, 1024, 1536};
static constexpr int U1J[21] = {0, 0, 0, 1, 1, 2, 2, 3, 3, 4, 4,
                                5, 5, 6, 6, 7, 7, 8, 8, 9, 9};
static constexpr int U1T[21] = {1, 2, 3, 2, 3, 2, 3, 2, 3, 2, 3,
                                2, 3, 2, 3, 2, 3, 2, 3, 2, 3};
// second user j (tau is always 1); -1 = none
static constexpr int U2J[21] = {-1, 1, -1, 2, -1, 3, -1, 4, -1, 5, -1,
                                6, -1, 7, -1, 8, -1, 9, -1, 10, -1};

static __device__ __forceinline__ float red8(float s) {
    // sum across each 8-lane group; all 8 lanes get the sum.
    int t;
    // quad_perm [1,0,3,2] : lane ^ 1
    t = __builtin_amdgcn_update_dpp(0, __builtin_bit_cast(int, s), 0xB1, 0xF, 0xF, true);
    s += __builtin_bit_cast(float, t);
    // quad_perm [2,3,0,1] : lane ^ 2
    t = __builtin_amdgcn_update_dpp(0, __builtin_bit_cast(int, s), 0x4E, 0xF, 0xF, true);
    s += __builtin_bit_cast(float, t);
    // row_half_mirror : lane i <-> 7-i (within 8-lane half-row)
    t = __builtin_amdgcn_update_dpp(0, __builtin_bit_cast(int, s), 0x141, 0xF, 0xF, true);
    s += __builtin_bit_cast(float, t);
    return s;
}

__global__ __launch_bounds__(256) void attn_kernel(
    const float* __restrict__ qkv,
    const float* __restrict__ scale_gain,       // [11,16]
    const float* __restrict__ W_qscale,         // [11,64]
    const float* __restrict__ identity_bypass,  // [16]
    const float* __restrict__ pos_bias,         // [44,16]
    float* __restrict__ att) {
    const int lane = threadIdx.x & 63;
    const int p = lane >> 3;   // position within wave, 0..7
    const int l = lane & 7;    // d-chunk (8 floats), 0..7

    // XCD-chunked swizzle: hw assigns block i -> XCD i%8; give XCD x the
    // contiguous strip range [x*512, (x+1)*512) so tap reach-back rows stay
    // in its own L2. grid = 4096 blocks (fixed), 4096 % 8 == 0 -> bijective.
    const int wg = blockIdx.x;
    const int swg = (wg & 7) * 512 + (wg >> 3);

    const int flat = (swg * 4 + (threadIdx.x >> 6)) * 8;  // first n of wave
    const int n = (flat & (PN - 1)) + p;
    const int h = (flat >> 11) & (PH - 1);
    const int b = flat >> 15;

    const size_t base_bn = (size_t)b * PN;
    const int col = h * PHD + l * 8;

    const float* qp = qkv + (base_bn + n) * (3 * PD) + col;
    const float4 qa = *(const float4*)qp;
    const float4 qb = *(const float4*)(qp + 4);
    const float4 k0a = *(const float4*)(qp + PD);
    const float4 k0b = *(const float4*)(qp + PD + 4);
    const float4 v0a = *(const float4*)(qp + 2 * PD);
    const float4 v0b = *(const float4*)(qp + 2 * PD + 4);

    auto dot8 = [](float4 a0, float4 a1, float4 b0, float4 b1) {
        float s = a0.x * b0.x;
        s = fmaf(a0.y, b0.y, s);
        s = fmaf(a0.z, b0.z, s);
        s = fmaf(a0.w, b0.w, s);
        s = fmaf(a1.x, b1.x, s);
        s = fmaf(a1.y, b1.y, s);
        s = fmaf(a1.z, b1.z, s);
        s = fmaf(a1.w, b1.w, s);
        return red8(s);
    };

    const float dot0 = dot8(qa, qb, k0a, k0b);  // k0 regs die here

    // gains = softmax(q @ W_qscale^T + scale_gain[:,h]) over 11 scales
    float g[NSC];
    float mx = -1e30f;
#pragma unroll
    for (int s = 0; s < NSC; s++) {
        const float* wp = W_qscale + s * PHD + l * 8;
        const float4 w0 = *(const float4*)wp;
        const float4 w1 = *(const float4*)(wp + 4);
        g[s] = dot8(qa, qb, w0, w1) + scale_gain[s * PH + h];
        mx = fmaxf(mx, g[s]);
    }
    float ssum = 0.f;
#pragma unroll
    for (int s = 0; s < NSC; s++) {
        g[s] = __expf(g[s] - mx);
        ssum += g[s];
    }
    const float inv = 1.f / ssum;
#pragma unroll
    for (int s = 0; s < NSC; s++) g[s] *= inv;

    const float D4c[4] = {0.4829629131445341f, 0.8365163037378079f,
                          0.2241438680420134f, -0.1294095225512604f};

    float4 o0, o1;
    float z;

    // ---- offset-0 block: 11 tau=0 taps + identity bypass, all scale v0.
    {
        const float bp = log1pf(__expf(identity_bypass[h]));  // softplus
        const float f0 = (dot0 > 0.f ? dot0 : __expf(dot0) - 1.f) + 1.f;
        float wsum = bp * f0;
#pragma unroll
        for (int j = 0; j < NSC; j++) {
            const float xx = dot0 + pos_bias[(j * 4) * PH + h];
            const float feat = (xx > 0.f ? xx : __expf(xx) - 1.f) + 1.f;
            wsum = fmaf(g[j], D4c[0] * feat, wsum);
        }
        z = wsum;
        o0.x = wsum * v0a.x;
        o0.y = wsum * v0a.y;
        o0.z = wsum * v0a.z;
        o0.w = wsum * v0a.w;
        o1.x = wsum * v0b.x;
        o1.y = wsum * v0b.y;
        o1.z = wsum * v0b.z;
        o1.w = wsum * v0b.w;
    }  // v0 regs die here

    // ---- distinct nonzero offsets (each used by 1-2 taps, sharing k/v rows)
#pragma unroll
    for (int t = 0; t < 21; t++) {
        const int off = OFFS[t];
        const bool valid = (n >= off);
        const int idx = valid ? (n - off) : 0;
        const float vm = valid ? 1.f : 0.f;
        const size_t rb = (base_bn + idx) * (3 * PD);
        const float* kp = qkv + rb + PD + col;
        const float* vp = qkv + rb + 2 * PD + col;
        const float4 k4a = *(const float4*)kp;
        const float4 k4b = *(const float4*)(kp + 4);
        const float4 v4a = *(const float4*)vp;
        const float4 v4b = *(const float4*)(vp + 4);
        const float dv = dot8(qa, qb, k4a, k4b) * vm;

        // user 1: (U1J[t], U1T[t])
        float wv, zacc;
        {
            const int j = U1J[t], tau = U1T[t];
            const float xx = dv + pos_bias[(j * 4 + tau) * PH + h];
            const float feat = (xx > 0.f ? xx : __expf(xx) - 1.f) + 1.f;
            const float wp = g[j] * (D4c[tau] * feat);
            zacc = fabsf(wp);  // = g * |coef| * feat  (g,feat >= 0)
            wv = wp;
        }
        // user 2: (U2J[t], tau=1) if present
        if (U2J[t] >= 0) {
            const int j = U2J[t];
            const float xx = dv + pos_bias[(j * 4 + 1) * PH + h];
            const float feat = (xx > 0.f ? xx : __expf(xx) - 1.f) + 1.f;
            const float wp = g[j] * (D4c[1] * feat);
            zacc += wp;  // coef > 0
            wv += wp;
        }
        z += zacc;
        wv *= vm;
        o0.x = fmaf(wv, v4a.x, o0.x);
        o0.y = fmaf(wv, v4a.y, o0.y);
        o0.z = fmaf(wv, v4a.z, o0.z);
        o0.w = fmaf(wv, v4a.w, o0.w);
        o1.x = fmaf(wv, v4b.x, o1.x);
        o1.y = fmaf(wv, v4b.y, o1.y);
        o1.z = fmaf(wv, v4b.z, o1.z);
        o1.w = fmaf(wv, v4b.w, o1.w);
    }

    const float zi = 1.f / (z + 1e-6f);
    float4 r0, r1;
    r0.x = o0.x * zi; r0.y = o0.y * zi; r0.z = o0.z * zi; r0.w = o0.w * zi;
    r1.x = o1.x * zi; r1.y = o1.y * zi; r1.z = o1.z * zi; r1.w = o1.w * zi;
    float* op = att + (base_bn + n) * PD + col;
    *(float4*)op = r0;
    *(float4*)(op + 4) = r1;
}

// ---------------- launch ----------------
extern "C" void kernel_launch(void* const* d_in, const int* in_sizes, int n_in,
                              void* d_out, int out_size, void* d_ws, size_t ws_size,
                              hipStream_t stream) {
    const float* x = (const float*)d_in[0];
    const float* W_qkv = (const float*)d_in[1];
    const float* b_qkv = (const float*)d_in[2];
    const float* W_out = (const float*)d_in[3];
    const float* b_out = (const float*)d_in[4];
    const float* W_gate = (const float*)d_in[5];
    const float* b_gate = (const float*)d_in[6];
    const float* scale_gain = (const float*)d_in[7];
    const float* W_qscale = (const float*)d_in[8];
    const float* identity_bypass = (const float*)d_in[9];
    const float* pos_bias = (const float*)d_in[10];
    float* out = (float*)d_out;

    const int M = PB * PN;  // 8192
    char* ws = (char*)d_ws;
    size_t off = 0;
    auto alloc = [&](size_t bytes) -> void* {
        void* p = ws + off;
        off += (bytes + 255) & ~(size_t)255;
        return p;
    };
    __hip_bfloat16* x_bf = (__hip_bfloat16*)alloc((size_t)M * PD * 2);
    __hip_bfloat16* wcomb_bf = (__hip_bfloat16*)alloc((size_t)4 * PD * PD * 2);
    __hip_bfloat16* wout_bf = (__hip_bfloat16*)alloc((size_t)PD * PD * 2);
    float* qkv = (float*)alloc((size_t)M * 3 * PD * 4);
    float* gate = (float*)alloc((size_t)M * PD * 4);
    float* att = (float*)alloc((size_t)M * PD * 4);
    __hip_bfloat16* gated = (__hip_bfloat16*)alloc((size_t)M * PD * 2);

    // casts
    cast_f32_to_bf16_v4<<<(M * PD / 4) / 256, 256, 0, stream>>>(
        (const float4*)x, (ushort4*)x_bf, M * PD / 4);
    cast_weights<<<(5 * PD * PD / 4) / 256, 256, 0, stream>>>(
        (const float4*)W_qkv, (const float4*)W_gate, (const float4*)W_out,
        (ushort4*)wcomb_bf, (ushort4*)wout_bf);

    // {qkv, gate} = x @ [W_qkv; W_gate]^T + {b_qkv, b_gate}  (256² pipeline)
    gemm_bt256<<<dim3(4 * PD / TBN, M / TBM), 512, 0, stream>>>(
        x_bf, wcomb_bf, b_qkv, b_gate, 3 * PD, qkv, 3 * PD, gate, PD, PD);

    // attention -> att fp32 [8192, 1024]   (8 positions per wave, 32 per block)
    attn_kernel<<<(PB * PH * PN) / 32, 256, 0, stream>>>(
        qkv, scale_gain, W_qscale, identity_bypass, pos_bias, att);

    // gated = bf16(att * sigmoid(gate))  (elementwise, HBM-bound ~12 us)
    gate_mul<<<(M * PD / 4) / 256, 256, 0, stream>>>(
        (const float4*)att, (const float4*)gate, (ushort4*)gated, M * PD / 4);

    // out = gated @ W_out^T + b_out  -> fp32  (N=1024 -> keep 128² for 512 blocks)
    gemm_bt128<<<dim3(PD / GBN, M / GBM), 256, 0, stream>>>(
        gated, wout_bf, b_out, b_out, PD, out, PD, out, PD, PD);
}